// Round 1
// baseline (379.532 us; speedup 1.0000x reference)
//
#include <hip/hip_runtime.h>
#include <cstdint>
#include <cstddef>

// ---------------------------------------------------------------------------
// DynaResidualBlock: hypernet GEMM -> per-sample 1x1 conv chain (bf16 MFMA)
//   FIN=64 FOUT=64 FH=128 LAT=512  B=16  H*W=16384
//   sizes = [8192,16384,16384,8192,4096,128,128,128,64,64], KTOT=53760
// ---------------------------------------------------------------------------

typedef short bf16x8 __attribute__((ext_vector_type(8)));   // 8 bf16 = 4 VGPRs
typedef float f32x16 __attribute__((ext_vector_type(16)));  // MFMA 32x32 acc

#define DEVFN static __device__ __forceinline__

// weight fragment counts (one frag = 32m x 16k = 512 bf16 = 1024 B, lane*16B)
// global ws frag order: in[0..16) mida[16..48) midb[48..80) out[80..96) short[96..104)
constexpr int NFRAG      = 104;
constexpr int WELEM      = 53248;           // bf16 weight elements per sample
constexpr int NSAMP      = 16;
constexpr size_t WS_WSHORTS = (size_t)WELEM;     // per-sample shorts
constexpr size_t WS_WBYTES_TOT = (size_t)NSAMP * WELEM * 2;  // 1,703,936

DEVFN unsigned bf16rne(float f) {
  unsigned u = __builtin_bit_cast(unsigned, f);
  return (u + 0x7fffu + ((u >> 16) & 1u)) >> 16;
}
DEVFN unsigned pk2(float lo, float hi) {
  return bf16rne(lo) | (bf16rne(hi) << 16);
}

// ---------------------------------------------------------------------------
// Kernel 1: ks = lat @ W.T + bias, scaled, scattered to frag-layout bf16 ws.
// grid 210 x 256 threads: thread t owns column n = blockIdx*256 + t (all 16 b)
// ---------------------------------------------------------------------------
__global__ __launch_bounds__(256) void hyper_gemm(
    const float* __restrict__ lat, const float* __restrict__ W,
    const float* __restrict__ bias, unsigned short* __restrict__ w_ws,
    float* __restrict__ b_ws) {
  __shared__ float Wl[256 * 66];  // 66-dword row stride: 2-way banks, 8B aligned
  const int t = threadIdx.x;
  const int n0 = blockIdx.x * 256;
  const int n = n0 + t;

  float acc[16];
#pragma unroll
  for (int b = 0; b < 16; ++b) acc[b] = 0.f;

#pragma unroll 1
  for (int kc = 0; kc < 8; ++kc) {
    __syncthreads();
    // coalesced load of W[n0..n0+256)[kc*64..+64) into LDS
#pragma unroll
    for (int i = 0; i < 16; ++i) {
      const int u = t + 256 * i;
      const int row = u >> 4, c4 = u & 15;
      const float4 v =
          *(const float4*)(W + (size_t)(n0 + row) * 512 + kc * 64 + c4 * 4);
      float* p = &Wl[row * 66 + c4 * 4];
      *(float2*)p = make_float2(v.x, v.y);
      *(float2*)(p + 2) = make_float2(v.z, v.w);
    }
    __syncthreads();
#pragma unroll
    for (int k4 = 0; k4 < 16; ++k4) {
      const float2 wa = *(const float2*)&Wl[t * 66 + k4 * 4];
      const float2 wb = *(const float2*)&Wl[t * 66 + k4 * 4 + 2];
      const float* lp = lat + kc * 64 + k4 * 4;  // uniform -> s_load
#pragma unroll
      for (int b = 0; b < 16; ++b) {
        const float* l4 = lp + b * 512;
        acc[b] = fmaf(wa.x, l4[0], acc[b]);
        acc[b] = fmaf(wa.y, l4[1], acc[b]);
        acc[b] = fmaf(wb.x, l4[2], acc[b]);
        acc[b] = fmaf(wb.y, l4[3], acc[b]);
      }
    }
  }

  const float bv = bias[n];
  if (n >= 53248) {  // conv biases: fp32, per-sample contiguous [512]
    const int j = n - 53248;
#pragma unroll
    for (int b = 0; b < 16; ++b) b_ws[b * 512 + j] = acc[b] + bv;
    return;
  }
  int fragbase, off, kbits;
  float scale;
  if (n < 8192)       { fragbase = 0;  off = 0;     kbits = 6; scale = 0.08838834764831845f; }
  else if (n < 24576) { fragbase = 16; off = 8192;  kbits = 7; scale = 0.08838834764831845f; }
  else if (n < 40960) { fragbase = 48; off = 24576; kbits = 7; scale = 0.08838834764831845f; }
  else if (n < 49152) { fragbase = 80; off = 40960; kbits = 7; scale = 0.125f; }
  else                { fragbase = 96; off = 49152; kbits = 6; scale = 0.125f; }
  const int r = n - off;
  const int m = r >> kbits;
  const int k = r & ((1 << kbits) - 1);
  const int mt = m >> 5, ks = k >> 4;
  const int lane = (m & 31) + 32 * ((k >> 3) & 1);
  const int j = k & 7;
  const int frag = fragbase + mt * (1 << (kbits - 4)) + ks;
  const size_t eoff = (size_t)frag * 512 + lane * 8 + j;  // in shorts
#pragma unroll
  for (int b = 0; b < 16; ++b) {
    const float v = (acc[b] + bv) * scale;
    w_ws[(size_t)b * WS_WSHORTS + eoff] = (unsigned short)bf16rne(v);
  }
}

// ---------------------------------------------------------------------------
// Kernel 2: per-sample conv chain. 256 blocks (sample = blk>>4, chunk = blk&15),
// 4 waves, each wave owns 64 pixels/iter, 4 iters (1024 px per block).
// ---------------------------------------------------------------------------

DEVFN f32x16 bias_init(const float* bl, int mt, int lh) {
  f32x16 a;
#pragma unroll
  for (int g = 0; g < 4; ++g) {
    const float4 bv = *(const float4*)&bl[mt * 32 + 8 * g + 4 * lh];
    a[4 * g + 0] = bv.x; a[4 * g + 1] = bv.y;
    a[4 * g + 2] = bv.z; a[4 * g + 3] = bv.w;
  }
  return a;
}

// write relu(acc) as bf16 into wave-private h buffer in B-frag layout
DEVFN void write_h(short* hb, int mt, int l31, int lh, const f32x16& a0,
                   const f32x16& a1) {
#pragma unroll
  for (int g = 0; g < 4; ++g) {
    const int kstep = mt * 2 + (g >> 1);
    const int sub = g & 1;
    const int base = (kstep * 2) * 512 + (l31 + 32 * sub) * 8 + lh * 4;
    uint2 w0, w1;
    w0.x = pk2(fmaxf(a0[4 * g + 0], 0.f), fmaxf(a0[4 * g + 1], 0.f));
    w0.y = pk2(fmaxf(a0[4 * g + 2], 0.f), fmaxf(a0[4 * g + 3], 0.f));
    w1.x = pk2(fmaxf(a1[4 * g + 0], 0.f), fmaxf(a1[4 * g + 1], 0.f));
    w1.y = pk2(fmaxf(a1[4 * g + 2], 0.f), fmaxf(a1[4 * g + 3], 0.f));
    *(uint2*)&hb[base] = w0;
    *(uint2*)&hb[base + 512] = w1;  // nt=1 frag
  }
}

#define MFMA32(A, B, C) __builtin_amdgcn_mfma_f32_32x32x16_bf16((A), (B), (C), 0, 0, 0)

__global__ __launch_bounds__(256, 1) void dyn_conv(
    const float* __restrict__ x, const unsigned short* __restrict__ w_ws,
    const float* __restrict__ b_ws, float* __restrict__ out) {
  // LDS frag order: in[0..16) midb[16..48) out[48..64) short[64..72); mida in regs
  __shared__ short wl[72 * 512];   // 73728 B
  __shared__ float bl[512];        //  2048 B
  __shared__ short hl[4][8192];    // 65536 B  (per-wave 16 frags, B-frag layout)

  const int s = blockIdx.x >> 4;
  const int chunk = blockIdx.x & 15;
  const int tid = threadIdx.x;
  const int wv = tid >> 6;
  const int l = tid & 63;
  const int l31 = l & 31;
  const int lh = l >> 5;

  const unsigned short* wbase = w_ws + (size_t)s * WS_WSHORTS;

  // stage in/midb/out/short weights -> LDS (frag layout preserved)
  for (int f = wv; f < 72; f += 4) {
    const int fg = (f < 16) ? f : f + 32;
    *(int4*)&wl[f * 512 + l * 8] = *(const int4*)&wbase[fg * 512 + l * 8];
  }
  bl[tid] = b_ws[s * 512 + tid];
  bl[tid + 256] = b_ws[s * 512 + tid + 256];

  // k_mida A-frags -> registers (32 frags = 128 VGPRs)
  bf16x8 Am[32];
#pragma unroll
  for (int i = 0; i < 32; ++i)
    Am[i] = *(const bf16x8*)&wbase[(16 + i) * 512 + l * 8];

  __syncthreads();

  short* hb = &hl[wv][0];

#pragma unroll 1
  for (int it = 0; it < 4; ++it) {
    const int px0 = chunk * 1024 + it * 256 + wv * 64;

    // x B-frags direct from global (reused by IN and SHORT stages)
    bf16x8 xf[2][4];
#pragma unroll
    for (int nt = 0; nt < 2; ++nt) {
#pragma unroll
      for (int ks = 0; ks < 4; ++ks) {
        const float* xp = x + (size_t)(s * 64 + ks * 16 + lh * 8) * 16384 +
                          px0 + nt * 32 + l31;
        float v[8];
#pragma unroll
        for (int j = 0; j < 8; ++j) v[j] = xp[(size_t)j * 16384];
        union { unsigned u[4]; bf16x8 v8; } uu;
#pragma unroll
        for (int j = 0; j < 4; ++j) uu.u[j] = pk2(v[2 * j], v[2 * j + 1]);
        xf[nt][ks] = uu.v8;
      }
    }

    // ---- stage IN: h1 = relu(k_in @ x + b_in)   (M=128, K=64)
#pragma unroll
    for (int mt = 0; mt < 4; ++mt) {
      f32x16 a0 = bias_init(bl + 0, mt, lh);
      f32x16 a1 = a0;
#pragma unroll
      for (int ks = 0; ks < 4; ++ks) {
        const bf16x8 A = *(const bf16x8*)&wl[(mt * 4 + ks) * 512 + l * 8];
        a0 = MFMA32(A, xf[0][ks], a0);
        a1 = MFMA32(A, xf[1][ks], a1);
      }
      write_h(hb, mt, l31, lh, a0, a1);
    }

    bf16x8 hB[16];

    // ---- stage MIDA (A from registers)          (M=128, K=128)
#pragma unroll
    for (int i = 0; i < 16; ++i) hB[i] = *(const bf16x8*)&hb[i * 512 + l * 8];
#pragma unroll
    for (int mt = 0; mt < 4; ++mt) {
      f32x16 a0 = bias_init(bl + 128, mt, lh);
      f32x16 a1 = a0;
#pragma unroll
      for (int ks = 0; ks < 8; ++ks) {
        a0 = MFMA32(Am[mt * 8 + ks], hB[ks * 2 + 0], a0);
        a1 = MFMA32(Am[mt * 8 + ks], hB[ks * 2 + 1], a1);
      }
      write_h(hb, mt, l31, lh, a0, a1);
    }

    // ---- stage MIDB (A from LDS)                (M=128, K=128)
#pragma unroll
    for (int i = 0; i < 16; ++i) hB[i] = *(const bf16x8*)&hb[i * 512 + l * 8];
#pragma unroll
    for (int mt = 0; mt < 4; ++mt) {
      f32x16 a0 = bias_init(bl + 256, mt, lh);
      f32x16 a1 = a0;
#pragma unroll
      for (int ks = 0; ks < 8; ++ks) {
        const bf16x8 A = *(const bf16x8*)&wl[(16 + mt * 8 + ks) * 512 + l * 8];
        a0 = MFMA32(A, hB[ks * 2 + 0], a0);
        a1 = MFMA32(A, hB[ks * 2 + 1], a1);
      }
      write_h(hb, mt, l31, lh, a0, a1);
    }

    // ---- stage OUT: out = k_out@h3 + k_short@x + b_out + b_short  (M=64)
#pragma unroll
    for (int i = 0; i < 16; ++i) hB[i] = *(const bf16x8*)&hb[i * 512 + l * 8];
#pragma unroll
    for (int mt = 0; mt < 2; ++mt) {
      f32x16 a0 = bias_init(bl + 384, mt, lh);
      {
        const f32x16 bs = bias_init(bl + 448, mt, lh);
#pragma unroll
        for (int e = 0; e < 16; ++e) a0[e] += bs[e];
      }
      f32x16 a1 = a0;
#pragma unroll
      for (int ks = 0; ks < 4; ++ks) {  // shortcut: K=64, B = x frags
        const bf16x8 A = *(const bf16x8*)&wl[(64 + mt * 4 + ks) * 512 + l * 8];
        a0 = MFMA32(A, xf[0][ks], a0);
        a1 = MFMA32(A, xf[1][ks], a1);
      }
#pragma unroll
      for (int ks = 0; ks < 8; ++ks) {  // k_out: K=128, B = h3
        const bf16x8 A = *(const bf16x8*)&wl[(48 + mt * 8 + ks) * 512 + l * 8];
        a0 = MFMA32(A, hB[ks * 2 + 0], a0);
        a1 = MFMA32(A, hB[ks * 2 + 1], a1);
      }
#pragma unroll
      for (int g = 0; g < 4; ++g) {
#pragma unroll
        for (int q = 0; q < 4; ++q) {
          const int row = mt * 32 + 8 * g + 4 * lh + q;
          float* op = out + (size_t)(s * 64 + row) * 16384 + px0 + l31;
          op[0]  = a0[4 * g + q];
          op[32] = a1[4 * g + q];
        }
      }
    }
  }
}

// ---------------------------------------------------------------------------
extern "C" void kernel_launch(void* const* d_in, const int* in_sizes, int n_in,
                              void* d_out, int out_size, void* d_ws,
                              size_t ws_size, hipStream_t stream) {
  (void)in_sizes; (void)n_in; (void)out_size; (void)ws_size;
  const float* x   = (const float*)d_in[0];
  const float* lat = (const float*)d_in[1];
  const float* W   = (const float*)d_in[2];
  const float* b   = (const float*)d_in[3];
  unsigned short* w_ws = (unsigned short*)d_ws;
  float* b_ws = (float*)((char*)d_ws + WS_WBYTES_TOT);
  float* out = (float*)d_out;

  hyper_gemm<<<dim3(210), dim3(256), 0, stream>>>(lat, W, b, w_ws, b_ws);
  dyn_conv<<<dim3(256), dim3(256), 0, stream>>>(x, w_ws, b_ws, out);
}

// Round 2
// 320.874 us; speedup vs baseline: 1.1828x; 1.1828x over previous
//
#include <hip/hip_runtime.h>
#include <cstdint>
#include <cstddef>

// ---------------------------------------------------------------------------
// DynaResidualBlock: hypernet GEMM -> per-sample 1x1 conv chain (bf16 MFMA)
//   FIN=64 FOUT=64 FH=128 LAT=512  B=16  H*W=16384
//   sizes = [8192,16384,16384,8192,4096,128,128,128,64,64], KTOT=53760
// ---------------------------------------------------------------------------

typedef short bf16x8 __attribute__((ext_vector_type(8)));   // 8 bf16 = 4 VGPRs
typedef float f32x16 __attribute__((ext_vector_type(16)));  // MFMA 32x32 acc

#define DEVFN static __device__ __forceinline__

// weight fragment counts (one frag = 32m x 16k = 512 bf16 = 1024 B, lane*16B)
// global ws frag order: in[0..16) mida[16..48) midb[48..80) out[80..96) short[96..104)
constexpr int WELEM      = 53248;           // bf16 weight elements per sample
constexpr int NSAMP      = 16;
constexpr size_t WS_WSHORTS = (size_t)WELEM;     // per-sample shorts
constexpr size_t WS_WBYTES_TOT = (size_t)NSAMP * WELEM * 2;  // 1,703,936

DEVFN unsigned bf16rne(float f) {
  unsigned u = __builtin_bit_cast(unsigned, f);
  return (u + 0x7fffu + ((u >> 16) & 1u)) >> 16;
}
DEVFN unsigned pk2(float lo, float hi) {
  return bf16rne(lo) | (bf16rne(hi) << 16);
}

// ---------------------------------------------------------------------------
// Kernel 1: ks = lat @ W.T + bias, scaled, scattered to frag-layout bf16 ws.
// 840 blocks x 128 thr. Block owns 64 columns (rows of W), K=512 in 8 chunks
// of 64. m97-style 2-barrier pipeline: next chunk held in regs during compute.
// Thread t: column c = t&63, k-half = t>>6 (32 k per chunk). lat ops scalar.
// ---------------------------------------------------------------------------
__global__ __launch_bounds__(128) void hyper_gemm(
    const float* __restrict__ lat, const float* __restrict__ W,
    const float* __restrict__ bias, unsigned short* __restrict__ w_ws,
    float* __restrict__ b_ws) {
  __shared__ float Wl[64 * 68];  // stride 68: b128 r/w both conflict-optimal
  const int t = threadIdx.x;
  const int n0 = blockIdx.x * 64;
  const int c = t & 63;
  const int half = __builtin_amdgcn_readfirstlane(t >> 6);  // wave-uniform

  const float* wp = W + (size_t)n0 * 512;
  float4 ld[8];

  auto loadW = [&](int kc) {
#pragma unroll
    for (int i = 0; i < 8; ++i) {
      const int u = t + 128 * i;
      const int row = u >> 4, c4 = u & 15;
      ld[i] = *(const float4*)(wp + (size_t)row * 512 + kc * 64 + c4 * 4);
    }
  };

  float acc[16];
#pragma unroll
  for (int b = 0; b < 16; ++b) acc[b] = 0.f;

  loadW(0);
#pragma unroll 1
  for (int kc = 0; kc < 8; ++kc) {
    // stage current chunk -> LDS
#pragma unroll
    for (int i = 0; i < 8; ++i) {
      const int u = t + 128 * i;
      const int row = u >> 4, c4 = u & 15;
      *(float4*)&Wl[row * 68 + c4 * 4] = ld[i];
    }
    __syncthreads();
    if (kc < 7) loadW(kc + 1);  // in flight across the whole compute phase

    const int kb = kc * 64 + half * 32;
#pragma unroll
    for (int j4 = 0; j4 < 8; ++j4) {
      const float4 wv = *(const float4*)&Wl[c * 68 + half * 32 + j4 * 4];
      const float* lp = lat + kb + j4 * 4;  // uniform address -> s_load
#pragma unroll
      for (int b = 0; b < 16; ++b) {
        const float4 lv = *(const float4*)(lp + (size_t)b * 512);
        acc[b] = fmaf(wv.x, lv.x, acc[b]);
        acc[b] = fmaf(wv.y, lv.y, acc[b]);
        acc[b] = fmaf(wv.z, lv.z, acc[b]);
        acc[b] = fmaf(wv.w, lv.w, acc[b]);
      }
    }
    __syncthreads();
  }

  // cross-half reduction through LDS (reuse Wl)
  float* red = Wl;
  if (half == 1) {
#pragma unroll
    for (int b = 0; b < 16; ++b) red[c * 17 + b] = acc[b];
  }
  __syncthreads();
  if (t < 64) {
#pragma unroll
    for (int b = 0; b < 16; ++b) acc[b] += red[c * 17 + b];

    const int n = n0 + c;
    const float bv = bias[n];
    if (n >= 53248) {  // conv biases: fp32, per-sample contiguous [512]
      const int j = n - 53248;
#pragma unroll
      for (int b = 0; b < 16; ++b) b_ws[b * 512 + j] = acc[b] + bv;
      return;
    }
    int fragbase, off, kbits;
    float scale;
    if (n < 8192)       { fragbase = 0;  off = 0;     kbits = 6; scale = 0.08838834764831845f; }
    else if (n < 24576) { fragbase = 16; off = 8192;  kbits = 7; scale = 0.08838834764831845f; }
    else if (n < 40960) { fragbase = 48; off = 24576; kbits = 7; scale = 0.08838834764831845f; }
    else if (n < 49152) { fragbase = 80; off = 40960; kbits = 7; scale = 0.125f; }
    else                { fragbase = 96; off = 49152; kbits = 6; scale = 0.125f; }
    const int r = n - off;
    const int m = r >> kbits;
    const int k = r & ((1 << kbits) - 1);
    const int mt = m >> 5, ks = k >> 4;
    const int lane = (m & 31) + 32 * ((k >> 3) & 1);
    const int j = k & 7;
    const int frag = fragbase + mt * (1 << (kbits - 4)) + ks;
    const size_t eoff = (size_t)frag * 512 + lane * 8 + j;  // in shorts
#pragma unroll
    for (int b = 0; b < 16; ++b) {
      const float v = (acc[b] + bv) * scale;
      w_ws[(size_t)b * WS_WSHORTS + eoff] = (unsigned short)bf16rne(v);
    }
  }
}

// ---------------------------------------------------------------------------
// Kernel 2: per-sample conv chain. 256 blocks (sample = blk>>4, chunk = blk&15),
// 4 waves, each wave owns 64 pixels/iter, 4 iters (1024 px per block).
// x loads for iter it+1 prefetched into registers while iter it computes.
// ---------------------------------------------------------------------------

DEVFN f32x16 bias_init(const float* bl, int mt, int lh) {
  f32x16 a;
#pragma unroll
  for (int g = 0; g < 4; ++g) {
    const float4 bv = *(const float4*)&bl[mt * 32 + 8 * g + 4 * lh];
    a[4 * g + 0] = bv.x; a[4 * g + 1] = bv.y;
    a[4 * g + 2] = bv.z; a[4 * g + 3] = bv.w;
  }
  return a;
}

// write relu(acc) as bf16 into wave-private h buffer in B-frag layout
DEVFN void write_h(short* hb, int mt, int l31, int lh, const f32x16& a0,
                   const f32x16& a1) {
#pragma unroll
  for (int g = 0; g < 4; ++g) {
    const int kstep = mt * 2 + (g >> 1);
    const int sub = g & 1;
    const int base = (kstep * 2) * 512 + (l31 + 32 * sub) * 8 + lh * 4;
    uint2 w0, w1;
    w0.x = pk2(fmaxf(a0[4 * g + 0], 0.f), fmaxf(a0[4 * g + 1], 0.f));
    w0.y = pk2(fmaxf(a0[4 * g + 2], 0.f), fmaxf(a0[4 * g + 3], 0.f));
    w1.x = pk2(fmaxf(a1[4 * g + 0], 0.f), fmaxf(a1[4 * g + 1], 0.f));
    w1.y = pk2(fmaxf(a1[4 * g + 2], 0.f), fmaxf(a1[4 * g + 3], 0.f));
    *(uint2*)&hb[base] = w0;
    *(uint2*)&hb[base + 512] = w1;  // nt=1 frag
  }
}

#define MFMA32(A, B, C) __builtin_amdgcn_mfma_f32_32x32x16_bf16((A), (B), (C), 0, 0, 0)

__global__ __launch_bounds__(256, 1) void dyn_conv(
    const float* __restrict__ x, const unsigned short* __restrict__ w_ws,
    const float* __restrict__ b_ws, float* __restrict__ out) {
  // LDS frag order: in[0..16) midb[16..48) out[48..64) short[64..72); mida in regs
  __shared__ short wl[72 * 512];   // 73728 B
  __shared__ float bl[512];        //  2048 B
  __shared__ short hl[4][8192];    // 65536 B  (per-wave 16 frags, B-frag layout)

  const int s = blockIdx.x >> 4;
  const int chunk = blockIdx.x & 15;
  const int tid = threadIdx.x;
  const int wv = tid >> 6;
  const int l = tid & 63;
  const int l31 = l & 31;
  const int lh = l >> 5;

  const unsigned short* wbase = w_ws + (size_t)s * WS_WSHORTS;

  // stage in/midb/out/short weights -> LDS (frag layout preserved)
  for (int f = wv; f < 72; f += 4) {
    const int fg = (f < 16) ? f : f + 32;
    *(int4*)&wl[f * 512 + l * 8] = *(const int4*)&wbase[fg * 512 + l * 8];
  }
  bl[tid] = b_ws[s * 512 + tid];
  bl[tid + 256] = b_ws[s * 512 + tid + 256];

  // k_mida A-frags -> registers (32 frags = 128 VGPRs)
  bf16x8 Am[32];
#pragma unroll
  for (int i = 0; i < 32; ++i)
    Am[i] = *(const bf16x8*)&wbase[(16 + i) * 512 + l * 8];

  // raw x for the current iteration, prefetched into registers
  const float* xbase = x + (size_t)(s * 64) * 16384;
  float xr[2][4][8];
  auto load_xr = [&](int it) {
    const int px0 = chunk * 1024 + it * 256 + wv * 64;
#pragma unroll
    for (int nt = 0; nt < 2; ++nt) {
#pragma unroll
      for (int ks = 0; ks < 4; ++ks) {
        const float* xp =
            xbase + (size_t)(ks * 16 + lh * 8) * 16384 + px0 + nt * 32 + l31;
#pragma unroll
        for (int j = 0; j < 8; ++j) xr[nt][ks][j] = xp[(size_t)j * 16384];
      }
    }
  };
  load_xr(0);

  __syncthreads();

  short* hb = &hl[wv][0];

#pragma unroll 1
  for (int it = 0; it < 4; ++it) {
    const int px0 = chunk * 1024 + it * 256 + wv * 64;

    // pack current x regs -> bf16 B-frags (reused by IN and SHORT stages)
    bf16x8 xf[2][4];
#pragma unroll
    for (int nt = 0; nt < 2; ++nt) {
#pragma unroll
      for (int ks = 0; ks < 4; ++ks) {
        union { unsigned u[4]; bf16x8 v8; } uu;
#pragma unroll
        for (int j = 0; j < 4; ++j)
          uu.u[j] = pk2(xr[nt][ks][2 * j], xr[nt][ks][2 * j + 1]);
        xf[nt][ks] = uu.v8;
      }
    }
    // prefetch next iteration's x; latency overlaps all four MFMA stages
    if (it < 3) load_xr(it + 1);

    // ---- stage IN: h1 = relu(k_in @ x + b_in)   (M=128, K=64)
#pragma unroll
    for (int mt = 0; mt < 4; ++mt) {
      f32x16 a0 = bias_init(bl + 0, mt, lh);
      f32x16 a1 = a0;
#pragma unroll
      for (int ks = 0; ks < 4; ++ks) {
        const bf16x8 A = *(const bf16x8*)&wl[(mt * 4 + ks) * 512 + l * 8];
        a0 = MFMA32(A, xf[0][ks], a0);
        a1 = MFMA32(A, xf[1][ks], a1);
      }
      write_h(hb, mt, l31, lh, a0, a1);
    }

    bf16x8 hB[16];

    // ---- stage MIDA (A from registers)          (M=128, K=128)
#pragma unroll
    for (int i = 0; i < 16; ++i) hB[i] = *(const bf16x8*)&hb[i * 512 + l * 8];
#pragma unroll
    for (int mt = 0; mt < 4; ++mt) {
      f32x16 a0 = bias_init(bl + 128, mt, lh);
      f32x16 a1 = a0;
#pragma unroll
      for (int ks = 0; ks < 8; ++ks) {
        a0 = MFMA32(Am[mt * 8 + ks], hB[ks * 2 + 0], a0);
        a1 = MFMA32(Am[mt * 8 + ks], hB[ks * 2 + 1], a1);
      }
      write_h(hb, mt, l31, lh, a0, a1);
    }

    // ---- stage MIDB (A from LDS)                (M=128, K=128)
#pragma unroll
    for (int i = 0; i < 16; ++i) hB[i] = *(const bf16x8*)&hb[i * 512 + l * 8];
#pragma unroll
    for (int mt = 0; mt < 4; ++mt) {
      f32x16 a0 = bias_init(bl + 256, mt, lh);
      f32x16 a1 = a0;
#pragma unroll
      for (int ks = 0; ks < 8; ++ks) {
        const bf16x8 A = *(const bf16x8*)&wl[(16 + mt * 8 + ks) * 512 + l * 8];
        a0 = MFMA32(A, hB[ks * 2 + 0], a0);
        a1 = MFMA32(A, hB[ks * 2 + 1], a1);
      }
      write_h(hb, mt, l31, lh, a0, a1);
    }

    // ---- stage OUT: out = k_out@h3 + k_short@x + b_out + b_short  (M=64)
#pragma unroll
    for (int i = 0; i < 16; ++i) hB[i] = *(const bf16x8*)&hb[i * 512 + l * 8];
#pragma unroll
    for (int mt = 0; mt < 2; ++mt) {
      f32x16 a0 = bias_init(bl + 384, mt, lh);
      {
        const f32x16 bs = bias_init(bl + 448, mt, lh);
#pragma unroll
        for (int e = 0; e < 16; ++e) a0[e] += bs[e];
      }
      f32x16 a1 = a0;
#pragma unroll
      for (int ks = 0; ks < 4; ++ks) {  // shortcut: K=64, B = x frags
        const bf16x8 A = *(const bf16x8*)&wl[(64 + mt * 4 + ks) * 512 + l * 8];
        a0 = MFMA32(A, xf[0][ks], a0);
        a1 = MFMA32(A, xf[1][ks], a1);
      }
#pragma unroll
      for (int ks = 0; ks < 8; ++ks) {  // k_out: K=128, B = h3
        const bf16x8 A = *(const bf16x8*)&wl[(48 + mt * 8 + ks) * 512 + l * 8];
        a0 = MFMA32(A, hB[ks * 2 + 0], a0);
        a1 = MFMA32(A, hB[ks * 2 + 1], a1);
      }
#pragma unroll
      for (int g = 0; g < 4; ++g) {
#pragma unroll
        for (int q = 0; q < 4; ++q) {
          const int row = mt * 32 + 8 * g + 4 * lh + q;
          float* op = out + (size_t)(s * 64 + row) * 16384 + px0 + l31;
          op[0]  = a0[4 * g + q];
          op[32] = a1[4 * g + q];
        }
      }
    }
  }
}

// ---------------------------------------------------------------------------
extern "C" void kernel_launch(void* const* d_in, const int* in_sizes, int n_in,
                              void* d_out, int out_size, void* d_ws,
                              size_t ws_size, hipStream_t stream) {
  (void)in_sizes; (void)n_in; (void)out_size; (void)ws_size;
  const float* x   = (const float*)d_in[0];
  const float* lat = (const float*)d_in[1];
  const float* W   = (const float*)d_in[2];
  const float* b   = (const float*)d_in[3];
  unsigned short* w_ws = (unsigned short*)d_ws;
  float* b_ws = (float*)((char*)d_ws + WS_WBYTES_TOT);
  float* out = (float*)d_out;

  hyper_gemm<<<dim3(840), dim3(128), 0, stream>>>(lat, W, b, w_ws, b_ws);
  dyn_conv<<<dim3(256), dim3(256), 0, stream>>>(x, w_ws, b_ws, out);
}

// Round 3
// 268.205 us; speedup vs baseline: 1.4151x; 1.1964x over previous
//
#include <hip/hip_runtime.h>
#include <cstdint>
#include <cstddef>

// ---------------------------------------------------------------------------
// DynaResidualBlock: hypernet GEMM (MFMA, hi/lo bf16 split = fp32-accurate)
//  -> per-sample 1x1 conv chain (bf16 MFMA)
//   FIN=64 FOUT=64 FH=128 LAT=512  B=16  H*W=16384
//   sizes = [8192,16384,16384,8192,4096,128,128,128,64,64], KTOT=53760
// ---------------------------------------------------------------------------

typedef short bf16x8 __attribute__((ext_vector_type(8)));   // 8 bf16 = 4 VGPRs
typedef float f32x4  __attribute__((ext_vector_type(4)));
typedef float f32x16 __attribute__((ext_vector_type(16)));  // MFMA 32x32 acc

#define DEVFN static __device__ __forceinline__

constexpr int WELEM      = 53248;           // bf16 weight elements per sample
constexpr size_t WS_WSHORTS = (size_t)WELEM;
constexpr size_t WS_WBYTES_TOT = (size_t)16 * WELEM * 2;     // 1,703,936
constexpr size_t WS_BOFF  = WS_WBYTES_TOT;                   // b_ws: 16*512 f32
constexpr size_t WS_AHOFF = WS_BOFF + 16 * 512 * 4;          // ah frags: 16 KB
constexpr size_t WS_ALOFF = WS_AHOFF + 16384;                // al frags: 16 KB

DEVFN unsigned bf16rne(float f) {
  unsigned u = __builtin_bit_cast(unsigned, f);
  return (u + 0x7fffu + ((u >> 16) & 1u)) >> 16;
}
DEVFN unsigned pk2(float lo, float hi) {
  return bf16rne(lo) | (bf16rne(hi) << 16);
}

// ---------------------------------------------------------------------------
// Kernel 0: lat -> hi/lo bf16 A-frags for mfma_16x16x32.
// frag element (s, lane l, j): A[m=l&15][k = s*32 + (l>>4)*8 + j]
// stored at ah_ws[(s*64+l)*8 + j]. 1024 (s,l) pairs.
// ---------------------------------------------------------------------------
__global__ __launch_bounds__(256) void lat_prep(
    const float* __restrict__ lat, unsigned short* __restrict__ ah_ws,
    unsigned short* __restrict__ al_ws) {
  const int id = blockIdx.x * 256 + threadIdx.x;  // 0..1023
  const int s = id >> 6, l = id & 63;
  const int m = l & 15, q = l >> 4;
  const float* ap = lat + m * 512 + s * 32 + q * 8;
  float f[8];
#pragma unroll
  for (int j = 0; j < 8; ++j) f[j] = ap[j];
  unsigned H[4], L[4];
#pragma unroll
  for (int p = 0; p < 4; ++p) {
    const unsigned u0 = __builtin_bit_cast(unsigned, f[2 * p]);
    const unsigned u1 = __builtin_bit_cast(unsigned, f[2 * p + 1]);
    const unsigned h0 = u0 & 0xFFFF0000u, h1 = u1 & 0xFFFF0000u;
    H[p] = (h0 >> 16) | h1;
    const float lo0 = f[2 * p] - __builtin_bit_cast(float, h0);
    const float lo1 = f[2 * p + 1] - __builtin_bit_cast(float, h1);
    L[p] = pk2(lo0, lo1);
  }
  *(uint4*)&ah_ws[(size_t)(s * 64 + l) * 8] = make_uint4(H[0], H[1], H[2], H[3]);
  *(uint4*)&al_ws[(size_t)(s * 64 + l) * 8] = make_uint4(L[0], L[1], L[2], L[3]);
}

// ---------------------------------------------------------------------------
// Kernel 1: ks = lat @ W.T + bias via MFMA 16x16x32 (hi/lo split, 3 mfma/step)
// One 16-column tile per wave; 3360 tiles = 840 blocks x 4 waves.
// Wave streams its 16 W rows (columns of ks) with an 8-step float4 ring
// (16 KB in flight per wave). Epilogue scatters to frag-layout bf16 ws.
// ---------------------------------------------------------------------------
#define MFMA16(A, B, C) __builtin_amdgcn_mfma_f32_16x16x32_bf16((A), (B), (C), 0, 0, 0)

__global__ __launch_bounds__(256, 2) void hyper_gemm(
    const float* __restrict__ W, const float* __restrict__ bias,
    const unsigned short* __restrict__ ah_ws,
    const unsigned short* __restrict__ al_ws,
    unsigned short* __restrict__ w_ws, float* __restrict__ b_ws) {
  const int tid = threadIdx.x;
  const int wv = tid >> 6;
  const int l = tid & 63;
  const int q = l >> 4;
  const int g = blockIdx.x * 4 + wv;  // tile id 0..3359
  const int n0 = g * 16;
  const int n = n0 + (l & 15);

  // A frags (shared by all waves; L2-hot)
  bf16x8 Ah[16], Al[16];
#pragma unroll
  for (int s = 0; s < 16; ++s) {
    Ah[s] = *(const bf16x8*)&ah_ws[(size_t)(s * 64 + l) * 8];
    Al[s] = *(const bf16x8*)&al_ws[(size_t)(s * 64 + l) * 8];
  }

  // B stream: lane reads W[n][s*32 + q*8 .. +8]
  const float* bp = W + (size_t)n * 512 + q * 8;
  float4 ld[8][2];
#pragma unroll
  for (int s = 0; s < 8; ++s) {
    ld[s][0] = *(const float4*)(bp + s * 32);
    ld[s][1] = *(const float4*)(bp + s * 32 + 4);
  }

  f32x4 acc = {0.f, 0.f, 0.f, 0.f};
#pragma unroll
  for (int s = 0; s < 16; ++s) {
    const float4 b0 = ld[s & 7][0];
    const float4 b1 = ld[s & 7][1];
    if (s < 8) {
      ld[s][0] = *(const float4*)(bp + (s + 8) * 32);
      ld[s][1] = *(const float4*)(bp + (s + 8) * 32 + 4);
    }
    const float f[8] = {b0.x, b0.y, b0.z, b0.w, b1.x, b1.y, b1.z, b1.w};
    union { unsigned u[4]; bf16x8 v; } BH, BL;
#pragma unroll
    for (int p = 0; p < 4; ++p) {
      const unsigned u0 = __builtin_bit_cast(unsigned, f[2 * p]);
      const unsigned u1 = __builtin_bit_cast(unsigned, f[2 * p + 1]);
      const unsigned h0 = u0 & 0xFFFF0000u, h1 = u1 & 0xFFFF0000u;
      BH.u[p] = (h0 >> 16) | h1;
      const float lo0 = f[2 * p] - __builtin_bit_cast(float, h0);
      const float lo1 = f[2 * p + 1] - __builtin_bit_cast(float, h1);
      BL.u[p] = pk2(lo0, lo1);
    }
    acc = MFMA16(Ah[s], BH.v, acc);
    acc = MFMA16(Ah[s], BL.v, acc);
    acc = MFMA16(Al[s], BH.v, acc);
  }

  // epilogue: lane holds column n, samples b = q*4 + r  (D: col=l&15, row=q*4+r)
  const float bv = bias[n];
  if (n0 >= 53248) {  // conv biases: fp32, per-sample contiguous [512]
    const int j = n - 53248;
#pragma unroll
    for (int r = 0; r < 4; ++r) b_ws[(q * 4 + r) * 512 + j] = acc[r] + bv;
    return;
  }
  int fragbase, off, kbits;
  float scale;
  if (n < 8192)       { fragbase = 0;  off = 0;     kbits = 6; scale = 0.08838834764831845f; }
  else if (n < 24576) { fragbase = 16; off = 8192;  kbits = 7; scale = 0.08838834764831845f; }
  else if (n < 40960) { fragbase = 48; off = 24576; kbits = 7; scale = 0.08838834764831845f; }
  else if (n < 49152) { fragbase = 80; off = 40960; kbits = 7; scale = 0.125f; }
  else                { fragbase = 96; off = 49152; kbits = 6; scale = 0.125f; }
  const int r0 = n - off;
  const int m = r0 >> kbits;
  const int k = r0 & ((1 << kbits) - 1);
  const int mt = m >> 5, ks = k >> 4;
  const int lane = (m & 31) + 32 * ((k >> 3) & 1);
  const int j = k & 7;
  const int frag = fragbase + mt * (1 << (kbits - 4)) + ks;
  const size_t eoff = (size_t)frag * 512 + lane * 8 + j;  // in shorts
#pragma unroll
  for (int r = 0; r < 4; ++r) {
    const float v = (acc[r] + bv) * scale;
    w_ws[(size_t)(q * 4 + r) * WS_WSHORTS + eoff] = (unsigned short)bf16rne(v);
  }
}

// ---------------------------------------------------------------------------
// Kernel 2: per-sample conv chain. 256 blocks (sample = blk>>4, chunk = blk&15),
// 4 waves, each wave owns 64 pixels/iter, 4 iters (1024 px per block).
// x loads for iter it+1 prefetched into registers while iter it computes.
// ---------------------------------------------------------------------------

DEVFN f32x16 bias_init(const float* bl, int mt, int lh) {
  f32x16 a;
#pragma unroll
  for (int g = 0; g < 4; ++g) {
    const float4 bv = *(const float4*)&bl[mt * 32 + 8 * g + 4 * lh];
    a[4 * g + 0] = bv.x; a[4 * g + 1] = bv.y;
    a[4 * g + 2] = bv.z; a[4 * g + 3] = bv.w;
  }
  return a;
}

// write relu(acc) as bf16 into wave-private h buffer in B-frag layout
DEVFN void write_h(short* hb, int mt, int l31, int lh, const f32x16& a0,
                   const f32x16& a1) {
#pragma unroll
  for (int g = 0; g < 4; ++g) {
    const int kstep = mt * 2 + (g >> 1);
    const int sub = g & 1;
    const int base = (kstep * 2) * 512 + (l31 + 32 * sub) * 8 + lh * 4;
    uint2 w0, w1;
    w0.x = pk2(fmaxf(a0[4 * g + 0], 0.f), fmaxf(a0[4 * g + 1], 0.f));
    w0.y = pk2(fmaxf(a0[4 * g + 2], 0.f), fmaxf(a0[4 * g + 3], 0.f));
    w1.x = pk2(fmaxf(a1[4 * g + 0], 0.f), fmaxf(a1[4 * g + 1], 0.f));
    w1.y = pk2(fmaxf(a1[4 * g + 2], 0.f), fmaxf(a1[4 * g + 3], 0.f));
    *(uint2*)&hb[base] = w0;
    *(uint2*)&hb[base + 512] = w1;  // nt=1 frag
  }
}

#define MFMA32(A, B, C) __builtin_amdgcn_mfma_f32_32x32x16_bf16((A), (B), (C), 0, 0, 0)

__global__ __launch_bounds__(256, 1) void dyn_conv(
    const float* __restrict__ x, const unsigned short* __restrict__ w_ws,
    const float* __restrict__ b_ws, float* __restrict__ out) {
  // LDS frag order: in[0..16) midb[16..48) out[48..64) short[64..72); mida in regs
  __shared__ short wl[72 * 512];   // 73728 B
  __shared__ float bl[512];        //  2048 B
  __shared__ short hl[4][8192];    // 65536 B  (per-wave 16 frags, B-frag layout)

  const int s = blockIdx.x >> 4;
  const int chunk = blockIdx.x & 15;
  const int tid = threadIdx.x;
  const int wv = tid >> 6;
  const int l = tid & 63;
  const int l31 = l & 31;
  const int lh = l >> 5;

  const unsigned short* wbase = w_ws + (size_t)s * WS_WSHORTS;

  // stage in/midb/out/short weights -> LDS (frag layout preserved)
  for (int f = wv; f < 72; f += 4) {
    const int fg = (f < 16) ? f : f + 32;
    *(int4*)&wl[f * 512 + l * 8] = *(const int4*)&wbase[fg * 512 + l * 8];
  }
  bl[tid] = b_ws[s * 512 + tid];
  bl[tid + 256] = b_ws[s * 512 + tid + 256];

  // k_mida A-frags -> registers (32 frags = 128 VGPRs)
  bf16x8 Am[32];
#pragma unroll
  for (int i = 0; i < 32; ++i)
    Am[i] = *(const bf16x8*)&wbase[(16 + i) * 512 + l * 8];

  // raw x for the current iteration, prefetched into registers
  const float* xbase = x + (size_t)(s * 64) * 16384;
  float xr[2][4][8];
  auto load_xr = [&](int it) {
    const int px0 = chunk * 1024 + it * 256 + wv * 64;
#pragma unroll
    for (int nt = 0; nt < 2; ++nt) {
#pragma unroll
      for (int ks = 0; ks < 4; ++ks) {
        const float* xp =
            xbase + (size_t)(ks * 16 + lh * 8) * 16384 + px0 + nt * 32 + l31;
#pragma unroll
        for (int j = 0; j < 8; ++j) xr[nt][ks][j] = xp[(size_t)j * 16384];
      }
    }
  };
  load_xr(0);

  __syncthreads();

  short* hb = &hl[wv][0];

#pragma unroll 1
  for (int it = 0; it < 4; ++it) {
    const int px0 = chunk * 1024 + it * 256 + wv * 64;

    // pack current x regs -> bf16 B-frags (reused by IN and SHORT stages)
    bf16x8 xf[2][4];
#pragma unroll
    for (int nt = 0; nt < 2; ++nt) {
#pragma unroll
      for (int ks = 0; ks < 4; ++ks) {
        union { unsigned u[4]; bf16x8 v8; } uu;
#pragma unroll
        for (int j = 0; j < 4; ++j)
          uu.u[j] = pk2(xr[nt][ks][2 * j], xr[nt][ks][2 * j + 1]);
        xf[nt][ks] = uu.v8;
      }
    }
    // prefetch next iteration's x; latency overlaps all four MFMA stages
    if (it < 3) load_xr(it + 1);

    // ---- stage IN: h1 = relu(k_in @ x + b_in)   (M=128, K=64)
#pragma unroll
    for (int mt = 0; mt < 4; ++mt) {
      f32x16 a0 = bias_init(bl + 0, mt, lh);
      f32x16 a1 = a0;
#pragma unroll
      for (int ks = 0; ks < 4; ++ks) {
        const bf16x8 A = *(const bf16x8*)&wl[(mt * 4 + ks) * 512 + l * 8];
        a0 = MFMA32(A, xf[0][ks], a0);
        a1 = MFMA32(A, xf[1][ks], a1);
      }
      write_h(hb, mt, l31, lh, a0, a1);
    }

    bf16x8 hB[16];

    // ---- stage MIDA (A from registers)          (M=128, K=128)
#pragma unroll
    for (int i = 0; i < 16; ++i) hB[i] = *(const bf16x8*)&hb[i * 512 + l * 8];
#pragma unroll
    for (int mt = 0; mt < 4; ++mt) {
      f32x16 a0 = bias_init(bl + 128, mt, lh);
      f32x16 a1 = a0;
#pragma unroll
      for (int ks = 0; ks < 8; ++ks) {
        a0 = MFMA32(Am[mt * 8 + ks], hB[ks * 2 + 0], a0);
        a1 = MFMA32(Am[mt * 8 + ks], hB[ks * 2 + 1], a1);
      }
      write_h(hb, mt, l31, lh, a0, a1);
    }

    // ---- stage MIDB (A from LDS)                (M=128, K=128)
#pragma unroll
    for (int i = 0; i < 16; ++i) hB[i] = *(const bf16x8*)&hb[i * 512 + l * 8];
#pragma unroll
    for (int mt = 0; mt < 4; ++mt) {
      f32x16 a0 = bias_init(bl + 256, mt, lh);
      f32x16 a1 = a0;
#pragma unroll
      for (int ks = 0; ks < 8; ++ks) {
        const bf16x8 A = *(const bf16x8*)&wl[(16 + mt * 8 + ks) * 512 + l * 8];
        a0 = MFMA32(A, hB[ks * 2 + 0], a0);
        a1 = MFMA32(A, hB[ks * 2 + 1], a1);
      }
      write_h(hb, mt, l31, lh, a0, a1);
    }

    // ---- stage OUT: out = k_out@h3 + k_short@x + b_out + b_short  (M=64)
#pragma unroll
    for (int i = 0; i < 16; ++i) hB[i] = *(const bf16x8*)&hb[i * 512 + l * 8];
#pragma unroll
    for (int mt = 0; mt < 2; ++mt) {
      f32x16 a0 = bias_init(bl + 384, mt, lh);
      {
        const f32x16 bs = bias_init(bl + 448, mt, lh);
#pragma unroll
        for (int e = 0; e < 16; ++e) a0[e] += bs[e];
      }
      f32x16 a1 = a0;
#pragma unroll
      for (int ks = 0; ks < 4; ++ks) {  // shortcut: K=64, B = x frags
        const bf16x8 A = *(const bf16x8*)&wl[(64 + mt * 4 + ks) * 512 + l * 8];
        a0 = MFMA32(A, xf[0][ks], a0);
        a1 = MFMA32(A, xf[1][ks], a1);
      }
#pragma unroll
      for (int ks = 0; ks < 8; ++ks) {  // k_out: K=128, B = h3
        const bf16x8 A = *(const bf16x8*)&wl[(48 + mt * 8 + ks) * 512 + l * 8];
        a0 = MFMA32(A, hB[ks * 2 + 0], a0);
        a1 = MFMA32(A, hB[ks * 2 + 1], a1);
      }
#pragma unroll
      for (int g = 0; g < 4; ++g) {
#pragma unroll
        for (int q = 0; q < 4; ++q) {
          const int row = mt * 32 + 8 * g + 4 * lh + q;
          float* op = out + (size_t)(s * 64 + row) * 16384 + px0 + l31;
          op[0]  = a0[4 * g + q];
          op[32] = a1[4 * g + q];
        }
      }
    }
  }
}

// ---------------------------------------------------------------------------
extern "C" void kernel_launch(void* const* d_in, const int* in_sizes, int n_in,
                              void* d_out, int out_size, void* d_ws,
                              size_t ws_size, hipStream_t stream) {
  (void)in_sizes; (void)n_in; (void)out_size; (void)ws_size;
  const float* x   = (const float*)d_in[0];
  const float* lat = (const float*)d_in[1];
  const float* W   = (const float*)d_in[2];
  const float* b   = (const float*)d_in[3];
  unsigned short* w_ws = (unsigned short*)d_ws;
  float* b_ws = (float*)((char*)d_ws + WS_BOFF);
  unsigned short* ah_ws = (unsigned short*)((char*)d_ws + WS_AHOFF);
  unsigned short* al_ws = (unsigned short*)((char*)d_ws + WS_ALOFF);
  float* out = (float*)d_out;

  lat_prep<<<dim3(4), dim3(256), 0, stream>>>(lat, ah_ws, al_ws);
  hyper_gemm<<<dim3(840), dim3(256), 0, stream>>>(W, b, ah_ws, al_ws, w_ws, b_ws);
  dyn_conv<<<dim3(256), dim3(256), 0, stream>>>(x, w_ws, b_ws, out);
}